// Round 3
// baseline (813.387 us; speedup 1.0000x reference)
//
#include <hip/hip_runtime.h>
#include <math.h>

#define B_ 32
#define C_ 512
#define L_ 8192
#define A_ 128

// -------- k1: qk[b,c] = (sum_a q[b,a] * Wk[a,c]) / sqrt(A),
//          q[b,a] = sum_c x[b,c,center] * Wq[a,c]
__global__ __launch_bounds__(128) void k1_qk(const float* __restrict__ x,
                                             const float* __restrict__ Wq,
                                             const float* __restrict__ Wk,
                                             const int* __restrict__ cidx,
                                             float* __restrict__ qk) {
  __shared__ float xc[C_];
  __shared__ float q[A_];
  const int b = blockIdx.x, tid = threadIdx.x;
  const int ci = cidx[0];
  const float* xb = x + (size_t)b * C_ * L_;
  for (int c = tid; c < C_; c += 128) xc[c] = xb[(size_t)c * L_ + ci];
  __syncthreads();
  {  // a = tid (A_ == 128 == blockDim)
    float acc = 0.f;
    const float* wq = Wq + tid * C_;
    for (int c = 0; c < C_; ++c) acc += xc[c] * wq[c];
    q[tid] = acc;
  }
  __syncthreads();
  const float scale = 0.08838834764831845f;  // 1/sqrt(128)
  for (int c = tid; c < C_; c += 128) {
    float s = 0.f;
    for (int a = 0; a < A_; ++a) s += q[a] * Wk[a * C_ + c];
    qk[b * C_ + c] = s * scale;
  }
}

// -------- k2: attn[b,l] = sum_c qk[b,c] * x[b,c,l]   (pass 1 over x)
// grid (L/512, B), 128 threads; each thread owns one float4 column of l.
__global__ __launch_bounds__(128) void k2_attn(const float* __restrict__ x,
                                               const float* __restrict__ qk,
                                               float* __restrict__ attn) {
  __shared__ float qks[C_];
  const int b = blockIdx.y, tid = threadIdx.x;
  const int l = blockIdx.x * 512 + tid * 4;
  for (int c = tid; c < C_; c += 128) qks[c] = qk[b * C_ + c];
  __syncthreads();
  const float* xb = x + (size_t)b * C_ * L_ + l;
  float4 acc = make_float4(0.f, 0.f, 0.f, 0.f);
#pragma unroll 8
  for (int c = 0; c < C_; ++c) {
    const float4 xv4 = *reinterpret_cast<const float4*>(xb + (size_t)c * L_);
    const float s = qks[c];
    acc.x += s * xv4.x;
    acc.y += s * xv4.y;
    acc.z += s * xv4.z;
    acc.w += s * xv4.w;
  }
  *reinterpret_cast<float4*>(attn + b * L_ + l) = acc;
}

// -------- k3: w[b,:] = softmax(attn[b,:])  — one block per b
__global__ __launch_bounds__(256) void k3_softmax(const float* __restrict__ attn,
                                                  float* __restrict__ w) {
  const int b = blockIdx.x, tid = threadIdx.x;
  const float* ab = attn + b * L_;
  float4 vals[8];
  float m = -INFINITY;
#pragma unroll
  for (int i = 0; i < 8; ++i) {
    vals[i] = *reinterpret_cast<const float4*>(ab + (size_t)(i * 256 + tid) * 4);
    m = fmaxf(m, fmaxf(fmaxf(vals[i].x, vals[i].y), fmaxf(vals[i].z, vals[i].w)));
  }
  __shared__ float sm[256];
  sm[tid] = m;
  __syncthreads();
  for (int s = 128; s > 0; s >>= 1) {
    if (tid < s) sm[tid] = fmaxf(sm[tid], sm[tid + s]);
    __syncthreads();
  }
  m = sm[0];
  __syncthreads();
  float sum = 0.f;
#pragma unroll
  for (int i = 0; i < 8; ++i) {
    vals[i].x = __expf(vals[i].x - m);
    vals[i].y = __expf(vals[i].y - m);
    vals[i].z = __expf(vals[i].z - m);
    vals[i].w = __expf(vals[i].w - m);
    sum += vals[i].x + vals[i].y + vals[i].z + vals[i].w;
  }
  sm[tid] = sum;
  __syncthreads();
  for (int s = 128; s > 0; s >>= 1) {
    if (tid < s) sm[tid] += sm[tid + s];
    __syncthreads();
  }
  const float inv = 1.f / sm[0];
  float* wb = w + b * L_;
#pragma unroll
  for (int i = 0; i < 8; ++i) {
    float4 o;
    o.x = vals[i].x * inv;
    o.y = vals[i].y * inv;
    o.z = vals[i].z * inv;
    o.w = vals[i].w * inv;
    *reinterpret_cast<float4*>(wb + (size_t)(i * 256 + tid) * 4) = o;
  }
}

// -------- k4: xv[b,c] = sum_l x[b,c,l] * w[b,l]   (pass 2 over x)
// grid (C, B), 256 threads per block; block reduces one row.
__global__ __launch_bounds__(256) void k4_xv(const float* __restrict__ x,
                                             const float* __restrict__ w,
                                             float* __restrict__ xv) {
  const int b = blockIdx.y, c = blockIdx.x, tid = threadIdx.x;
  const float* row = x + ((size_t)b * C_ + c) * L_;
  const float* wb = w + b * L_;
  float acc = 0.f;
#pragma unroll
  for (int i = 0; i < 8; ++i) {
    const int l = (i * 256 + tid) * 4;
    const float4 xr = *reinterpret_cast<const float4*>(row + l);
    const float4 wr = *reinterpret_cast<const float4*>(wb + l);
    acc += xr.x * wr.x + xr.y * wr.y + xr.z * wr.z + xr.w * wr.w;
  }
  __shared__ float sm[256];
  sm[tid] = acc;
  __syncthreads();
  for (int s = 128; s > 0; s >>= 1) {
    if (tid < s) sm[tid] += sm[tid + s];
    __syncthreads();
  }
  if (tid == 0) xv[b * C_ + c] = sm[0];
}

// -------- k5: out[b,co] = sum_a (sum_c Wv[a,c]*xv[b,c]) * Wout[co,a]
__global__ __launch_bounds__(128) void k5_out(const float* __restrict__ xv,
                                              const float* __restrict__ Wv,
                                              const float* __restrict__ Wout,
                                              float* __restrict__ out) {
  __shared__ float xvs[C_];
  __shared__ float pv[A_];
  const int b = blockIdx.x, tid = threadIdx.x;
  for (int c = tid; c < C_; c += 128) xvs[c] = xv[b * C_ + c];
  __syncthreads();
  {
    float acc = 0.f;
    const float* wv = Wv + tid * C_;
    for (int c = 0; c < C_; ++c) acc += xvs[c] * wv[c];
    pv[tid] = acc;
  }
  __syncthreads();
  for (int co = tid; co < C_; co += 128) {
    float acc = 0.f;
    const float* wo = Wout + co * A_;
    for (int a = 0; a < A_; ++a) acc += pv[a] * wo[a];
    out[b * C_ + co] = acc;
  }
}

extern "C" void kernel_launch(void* const* d_in, const int* in_sizes, int n_in,
                              void* d_out, int out_size, void* d_ws, size_t ws_size,
                              hipStream_t stream) {
  const float* x = (const float*)d_in[0];
  const float* Wq = (const float*)d_in[1];
  const float* Wk = (const float*)d_in[2];
  const float* Wv = (const float*)d_in[3];
  const float* Wout = (const float*)d_in[4];
  const int* cidx = (const int*)d_in[5];

  float* out_pooled = (float*)d_out;           // B*C floats
  float* out_w = out_pooled + B_ * C_;         // B*L floats

  float* qk = (float*)d_ws;                    // B*C
  float* attn = qk + B_ * C_;                  // B*L
  float* xv = attn + (size_t)B_ * L_;          // B*C

  k1_qk<<<B_, 128, 0, stream>>>(x, Wq, Wk, cidx, qk);
  k2_attn<<<dim3(L_ / 512, B_), 128, 0, stream>>>(x, qk, attn);
  k3_softmax<<<B_, 256, 0, stream>>>(attn, out_w);
  k4_xv<<<dim3(C_, B_), 256, 0, stream>>>(x, out_w, xv);
  k5_out<<<B_, 128, 0, stream>>>(xv, Wv, Wout, out_pooled);
}

// Round 4
// 790.112 us; speedup vs baseline: 1.0295x; 1.0295x over previous
//
#include <hip/hip_runtime.h>
#include <math.h>

#define B_ 32
#define C_ 512
#define L_ 8192
#define A_ 128
#define LT_ 32                // l-tile per fused block
#define NBLK_ (L_ / LT_)      // 256 l-tiles per batch

// -------- k1: qk[b,c] = (sum_a q[b,a] * Wk[a,c]) / sqrt(A),
//          q[b,a] = sum_c x[b,c,center] * Wq[a,c]
__global__ __launch_bounds__(128) void k1_qk(const float* __restrict__ x,
                                             const float* __restrict__ Wq,
                                             const float* __restrict__ Wk,
                                             const int* __restrict__ cidx,
                                             float* __restrict__ qk) {
  __shared__ float xc[C_];
  __shared__ float q[A_];
  const int b = blockIdx.x, tid = threadIdx.x;
  const int ci = cidx[0];
  const float* xb = x + (size_t)b * C_ * L_;
  for (int c = tid; c < C_; c += 128) xc[c] = xb[(size_t)c * L_ + ci];
  __syncthreads();
  {  // a = tid (A_ == 128 == blockDim)
    float acc = 0.f;
    const float* wq = Wq + tid * C_;
    for (int c = 0; c < C_; ++c) acc += xc[c] * wq[c];
    q[tid] = acc;
  }
  __syncthreads();
  const float scale = 0.08838834764831845f;  // 1/sqrt(128)
  for (int c = tid; c < C_; c += 128) {
    float s = 0.f;
    for (int a = 0; a < A_; ++a) s += q[a] * Wk[a * C_ + c];
    qk[b * C_ + c] = s * scale;
  }
}

// -------- kf: fused — stage x-tile in LDS once, compute attn logits,
//          local softmax (m,Z), and weighted xv partials. x read ONCE.
__global__ __launch_bounds__(256) void kf_fused(const float* __restrict__ x,
                                                const float* __restrict__ qk,
                                                float* __restrict__ attn,
                                                float* __restrict__ mpart,
                                                float* __restrict__ zpart,
                                                float* __restrict__ xvp) {
  __shared__ float xs[C_][LT_ + 1];   // +1 pad: all phases conflict-free
  __shared__ float qks[C_];
  __shared__ float p[LT_];
  __shared__ float red[8][LT_];
  const int tid = threadIdx.x;
  const int blk = blockIdx.x;   // l-tile
  const int b = blockIdx.y;
  const int l0 = blk * LT_;
  const float* xb = x + (size_t)b * C_ * L_;

  // ---- stage: 512c x 32l tile (64 KB), 16 float4 per thread
  qks[tid] = qk[b * C_ + tid];
  qks[tid + 256] = qk[b * C_ + tid + 256];
#pragma unroll
  for (int i = 0; i < 16; ++i) {
    const int idx = i * 256 + tid;        // float4 index, 8 per c-row
    const int c = idx >> 3;
    const int li = (idx & 7) * 4;
    const float4 v = *reinterpret_cast<const float4*>(xb + (size_t)c * L_ + l0 + li);
    xs[c][li] = v.x; xs[c][li + 1] = v.y; xs[c][li + 2] = v.z; xs[c][li + 3] = v.w;
  }
  __syncthreads();

  // ---- attn logits: thread (l = tid&31, g = tid>>5) sums 64 c
  const int l = tid & 31, g = tid >> 5;
  {
    float part = 0.f;
    const int cbase = g * 64;
#pragma unroll 8
    for (int c = cbase; c < cbase + 64; ++c) part += qks[c] * xs[c][l];
    red[g][l] = part;
  }
  __syncthreads();
  if (tid < 32) {
    float a = 0.f;
#pragma unroll
    for (int gg = 0; gg < 8; ++gg) a += red[gg][l];
    attn[b * L_ + l0 + l] = a;                    // unnormalized logit
    float m = a;
#pragma unroll
    for (int o = 16; o > 0; o >>= 1) m = fmaxf(m, __shfl_xor(m, o, 32));
    const float pv = __expf(a - m);
    float z = pv;
#pragma unroll
    for (int o = 16; o > 0; o >>= 1) z += __shfl_xor(z, o, 32);
    p[l] = pv;
    if (l == 0) { mpart[b * NBLK_ + blk] = m; zpart[b * NBLK_ + blk] = z; }
  }
  __syncthreads();

  // ---- xv partials: thread owns c = tid, tid+256
#pragma unroll
  for (int k = 0; k < 2; ++k) {
    const int c = tid + k * 256;
    float acc = 0.f;
#pragma unroll
    for (int ll = 0; ll < LT_; ++ll) acc += p[ll] * xs[c][ll];
    xvp[((size_t)b * NBLK_ + blk) * C_ + c] = acc;
  }
}

// -------- kc1: per-b global max/sum over 256 tile-partials, write scales + w
__global__ __launch_bounds__(256) void kc1(const float* __restrict__ mpart,
                                           const float* __restrict__ zpart,
                                           const float* __restrict__ attn,
                                           float* __restrict__ sc,
                                           float* __restrict__ minvz,
                                           float* __restrict__ w) {
  const int b = blockIdx.x, tid = threadIdx.x;  // NBLK_ == 256 == blockDim
  __shared__ float sm[256];
  const float m = mpart[b * NBLK_ + tid];
  sm[tid] = m;
  __syncthreads();
  for (int s = 128; s > 0; s >>= 1) {
    if (tid < s) sm[tid] = fmaxf(sm[tid], sm[tid + s]);
    __syncthreads();
  }
  const float M = sm[0];
  __syncthreads();
  const float e = __expf(m - M);
  sm[tid] = e * zpart[b * NBLK_ + tid];
  __syncthreads();
  for (int s = 128; s > 0; s >>= 1) {
    if (tid < s) sm[tid] += sm[tid + s];
    __syncthreads();
  }
  const float invZ = 1.f / sm[0];
  sc[b * NBLK_ + tid] = e;
  if (tid == 0) { minvz[b * 2] = M; minvz[b * 2 + 1] = invZ; }
  // w output
  const float* ab = attn + b * L_;
  float* wb = w + b * L_;
#pragma unroll
  for (int i = 0; i < 8; ++i) {
    const int li = (i * 256 + tid) * 4;
    float4 v = *reinterpret_cast<const float4*>(ab + li);
    v.x = __expf(v.x - M) * invZ;
    v.y = __expf(v.y - M) * invZ;
    v.z = __expf(v.z - M) * invZ;
    v.w = __expf(v.w - M) * invZ;
    *reinterpret_cast<float4*>(wb + li) = v;
  }
}

// -------- kc2: xv[b,c] = invZ * sum_blk sc[blk] * xvp[b,blk,c]
// grid (8, B): block covers 64 c; 4 blk-groups of 64 across threads.
__global__ __launch_bounds__(256) void kc2(const float* __restrict__ xvp,
                                           const float* __restrict__ sc,
                                           const float* __restrict__ minvz,
                                           float* __restrict__ xv) {
  const int b = blockIdx.y, cg = blockIdx.x, tid = threadIdx.x;
  const int cl = tid & 63, bs = tid >> 6;
  __shared__ float red[4][64];
  const float* base = xvp + (size_t)b * NBLK_ * C_ + cg * 64 + cl;
  const float* scb = sc + b * NBLK_;
  float acc = 0.f;
  for (int blk = bs * 64; blk < bs * 64 + 64; ++blk)
    acc += scb[blk] * base[(size_t)blk * C_];
  red[bs][cl] = acc;
  __syncthreads();
  if (tid < 64) {
    const float v = red[0][tid] + red[1][tid] + red[2][tid] + red[3][tid];
    xv[b * C_ + cg * 64 + tid] = v * minvz[b * 2 + 1];
  }
}

// -------- k5: out[b,co] = sum_a (sum_c Wv[a,c]*xv[b,c]) * Wout[co,a]
__global__ __launch_bounds__(128) void k5_out(const float* __restrict__ xv,
                                              const float* __restrict__ Wv,
                                              const float* __restrict__ Wout,
                                              float* __restrict__ out) {
  __shared__ float xvs[C_];
  __shared__ float pv[A_];
  const int b = blockIdx.x, tid = threadIdx.x;
  for (int c = tid; c < C_; c += 128) xvs[c] = xv[b * C_ + c];
  __syncthreads();
  {
    float acc = 0.f;
    const float* wv = Wv + tid * C_;
    for (int c = 0; c < C_; ++c) acc += xvs[c] * wv[c];
    pv[tid] = acc;
  }
  __syncthreads();
  for (int co = tid; co < C_; co += 128) {
    float acc = 0.f;
    const float* wo = Wout + co * A_;
    for (int a = 0; a < A_; ++a) acc += pv[a] * wo[a];
    out[b * C_ + co] = acc;
  }
}

extern "C" void kernel_launch(void* const* d_in, const int* in_sizes, int n_in,
                              void* d_out, int out_size, void* d_ws, size_t ws_size,
                              hipStream_t stream) {
  const float* x = (const float*)d_in[0];
  const float* Wq = (const float*)d_in[1];
  const float* Wk = (const float*)d_in[2];
  const float* Wv = (const float*)d_in[3];
  const float* Wout = (const float*)d_in[4];
  const int* cidx = (const int*)d_in[5];

  float* out_pooled = (float*)d_out;        // B*C
  float* out_w = out_pooled + B_ * C_;      // B*L

  float* p = (float*)d_ws;
  float* qk = p;        p += B_ * C_;             // 16384
  float* attn = p;      p += (size_t)B_ * L_;     // 262144
  float* mpart = p;     p += B_ * NBLK_;          // 8192
  float* zpart = p;     p += B_ * NBLK_;          // 8192
  float* sc = p;        p += B_ * NBLK_;          // 8192
  float* minvz = p;     p += B_ * 2;              // 64
  float* xvp = p;       p += (size_t)B_ * NBLK_ * C_;  // 4.19M
  float* xv = p;        p += B_ * C_;             // 16384

  k1_qk<<<B_, 128, 0, stream>>>(x, Wq, Wk, cidx, qk);
  kf_fused<<<dim3(NBLK_, B_), 256, 0, stream>>>(x, qk, attn, mpart, zpart, xvp);
  kc1<<<B_, 256, 0, stream>>>(mpart, zpart, attn, sc, minvz, out_w);
  kc2<<<dim3(8, B_), 256, 0, stream>>>(xvp, sc, minvz, xv);
  k5_out<<<B_, 128, 0, stream>>>(xv, Wv, Wout, out_pooled);
}